// Round 4
// baseline (222.210 us; speedup 1.0000x reference)
//
#include <hip/hip_runtime.h>
#include <cstdint>

// Problem constants: B=8, N=1024, C=256, heads=4, hd=64
typedef _Float16 h16;
typedef __attribute__((ext_vector_type(8))) _Float16 f16x8;
typedef __attribute__((ext_vector_type(4))) _Float16 f16x4;
typedef __attribute__((ext_vector_type(4))) float f32x4;

#define L2E 1.44269504f  // log2(e)

// ---------------------------------------------------------------------------
// 1) cast x,qkv_w,proj_w -> fp16; fused xm row-mean (wave per row on x part)
__global__ void k_cast(const float* __restrict__ x, const float* __restrict__ qw,
                       const float* __restrict__ pw, h16* __restrict__ xh,
                       h16* __restrict__ qwh, h16* __restrict__ pwh,
                       float* __restrict__ xm) {
  int bid = blockIdx.x, tid = threadIdx.x;
  if (bid < 2048) {  // x part
    int i4 = bid * 256 + tid;
    float4 v = ((const float4*)x)[i4];
    f16x4 o = {(h16)v.x, (h16)v.y, (h16)v.z, (h16)v.w};
    ((f16x4*)xh)[i4] = o;
    float s = v.x + v.y + v.z + v.w;
#pragma unroll
    for (int off = 32; off; off >>= 1) s += __shfl_xor(s, off);
    if ((tid & 63) == 0) xm[i4 >> 6] = s * (1.0f / 256.0f);
  } else {
    int i4 = (bid - 2048) * 256 + tid;
    if (i4 < 49152) {
      float4 v = ((const float4*)qw)[i4];
      f16x4 o = {(h16)v.x, (h16)v.y, (h16)v.z, (h16)v.w};
      ((f16x4*)qwh)[i4] = o;
    } else {
      int j = i4 - 49152;
      float4 v = ((const float4*)pw)[j];
      f16x4 o = {(h16)v.x, (h16)v.y, (h16)v.z, (h16)v.w};
      ((f16x4*)pwh)[j] = o;
    }
  }
}

// ---------------------------------------------------------------------------
// 2) amap[b,n] = sigmoid(conv3x3(xm_grid, mean_k(kernels)))  (zero pad)
__global__ void k_amap(const float* __restrict__ xm,
                       const float* __restrict__ kern,
                       float* __restrict__ amap) {
  int idx = blockIdx.x * 256 + threadIdx.x;  // 8192
  int b = idx >> 10, n = idx & 1023;
  int y = n >> 5, xq = n & 31;
  float km[9];
#pragma unroll
  for (int i = 0; i < 9; ++i)
    km[i] = 0.25f * (kern[i] + kern[9 + i] + kern[18 + i] + kern[27 + i]);
  float acc = 0.f;
#pragma unroll
  for (int dy = 0; dy < 3; ++dy) {
#pragma unroll
    for (int dx = 0; dx < 3; ++dx) {
      int yy = y + dy - 1, xx = xq + dx - 1;
      if (yy >= 0 && yy < 32 && xx >= 0 && xx < 32)
        acc += km[dy * 3 + dx] * xm[(b << 10) + (yy << 5) + xx];
    }
  }
  amap[idx] = 1.0f / (1.0f + __expf(-acc));
}

// ---------------------------------------------------------------------------
// 3) QKV GEMM via MFMA (fp16 in, fp32 acc): Q/K -> [b,h,n,64], V -> [b,h,64,n]
__global__ __launch_bounds__(128) void k_qkv(
    const h16* __restrict__ xh, const h16* __restrict__ qwh,
    const float* __restrict__ bias, h16* __restrict__ Qh,
    h16* __restrict__ Kh, h16* __restrict__ Vt) {
  const int w = threadIdx.x >> 6, lane = threadIdx.x & 63;
  const int g = lane >> 4, li = lane & 15;
  const int tile = blockIdx.x * 2 + w;  // 0..3071
  const int tr = tile & 255, tc = tile >> 8;
  const int r0 = tr * 32, c0 = tc * 64;
  f32x4 acc[2][4];
#pragma unroll
  for (int mr = 0; mr < 2; ++mr)
#pragma unroll
    for (int nc = 0; nc < 4; ++nc) acc[mr][nc] = {0.f, 0.f, 0.f, 0.f};
  for (int ks = 0; ks < 8; ++ks) {
    int k0 = ks * 32 + g * 8;
    f16x8 a[2], bf[4];
#pragma unroll
    for (int mr = 0; mr < 2; ++mr)
      a[mr] = *(const f16x8*)(xh + (size_t)(r0 + mr * 16 + li) * 256 + k0);
#pragma unroll
    for (int nc = 0; nc < 4; ++nc)
      bf[nc] = *(const f16x8*)(qwh + (size_t)(c0 + nc * 16 + li) * 256 + k0);
#pragma unroll
    for (int mr = 0; mr < 2; ++mr)
#pragma unroll
      for (int nc = 0; nc < 4; ++nc)
        acc[mr][nc] = __builtin_amdgcn_mfma_f32_16x16x32_f16(a[mr], bf[nc],
                                                             acc[mr][nc], 0, 0, 0);
  }
  const int which = c0 >> 8;
  const int hh = (c0 >> 6) & 3;
#pragma unroll
  for (int nc = 0; nc < 4; ++nc) {
    int d = nc * 16 + li;
    float bv = bias[c0 + d];
#pragma unroll
    for (int mr = 0; mr < 2; ++mr) {
#pragma unroll
      for (int r = 0; r < 4; ++r) {
        int m = r0 + mr * 16 + g * 4 + r;
        int bq = m >> 10, n = m & 1023;
        float v = acc[mr][nc][r] + bv;
        size_t base = ((size_t)(bq * 4 + hh)) << 16;
        if (which == 0) Qh[base + (size_t)n * 64 + d] = (h16)v;
        else if (which == 1) Kh[base + (size_t)n * 64 + d] = (h16)v;
        else Vt[base + (size_t)d * 1024 + n] = (h16)v;
      }
    }
  }
}

// ---------------------------------------------------------------------------
// 4) Kmax[bh] = max_n ||K[bh,n,:]||  (one block per bh)
__global__ void k_knorm(const h16* __restrict__ Kh, float* __restrict__ Kmaxb) {
  __shared__ float red[4];
  const int tid = threadIdx.x;
  const h16* base = Kh + ((size_t)blockIdx.x << 16);
  float mx = 0.f;
#pragma unroll
  for (int i = 0; i < 4; ++i) {
    int n = i * 256 + tid;
    float s2 = 0.f;
#pragma unroll
    for (int ks = 0; ks < 8; ++ks) {
      f16x8 v = *(const f16x8*)(base + (size_t)n * 64 + ks * 8);
#pragma unroll
      for (int e = 0; e < 8; ++e) {
        float f = (float)v[e];
        s2 += f * f;
      }
    }
    mx = fmaxf(mx, s2);
  }
#pragma unroll
  for (int off = 32; off; off >>= 1) mx = fmaxf(mx, __shfl_xor(mx, off));
  if ((tid & 63) == 0) red[tid >> 6] = mx;
  __syncthreads();
  if (tid == 0) {
    mx = fmaxf(fmaxf(red[0], red[1]), fmaxf(red[2], red[3]));
    Kmaxb[blockIdx.x] = sqrtf(mx);
  }
}

// ---------------------------------------------------------------------------
// 5) single-pass fused attention with shift-bound softmax.
//    block = (b, 16-row tile), 8 waves: wave = (head, j-half).
//    Writes unnormalized P (fp16) + rinv; PV accumulated and rescaled here.
__global__ __launch_bounds__(512, 4) void k_attn(
    const h16* __restrict__ Qh, const h16* __restrict__ Kh,
    const h16* __restrict__ Vt, const float* __restrict__ amap,
    const float* __restrict__ Kmaxb, h16* __restrict__ Pg,
    float* __restrict__ rinvb, h16* __restrict__ OHh) {
  __shared__ float am_s[1024];
  __shared__ float Lsh[4][2][16];
  __shared__ float Osh[4][16][64];
  __shared__ __align__(16) unsigned char Pst[8][2048];  // per-wave 16x64 h16, swizzled

  const int tid = threadIdx.x;
  const int wave = tid >> 6, lane = tid & 63, g = lane >> 4, li = lane & 15;
  const int h = wave >> 1, jh = wave & 1;
  const int b = blockIdx.x & 7, rt = blockIdx.x >> 3;
  const int r0 = rt * 16;
  const int bh = b * 4 + h;
  const size_t base = ((size_t)bh) << 16;

  am_s[tid] = amap[(b << 10) + tid];
  am_s[tid + 512] = amap[(b << 10) + 512 + tid];
  __syncthreads();

  // Q fragments (16 rows)
  f16x8 qf[2];
#pragma unroll
  for (int ks = 0; ks < 2; ++ks)
    qf[ks] = *(const f16x8*)(Qh + base + (size_t)(r0 + li) * 64 + ks * 32 + g * 8);

  // shift bound c_i = 0.125*||q_i||*Kmax + 0.1 (+margin), scaled by log2(e)
  float nq2 = 0.f;
#pragma unroll
  for (int ks = 0; ks < 2; ++ks)
#pragma unroll
    for (int e = 0; e < 8; ++e) {
      float f = (float)qf[ks][e];
      nq2 += f * f;
    }
  nq2 += __shfl_xor(nq2, 16);
  nq2 += __shfl_xor(nq2, 32);
  float c_li = 0.125f * sqrtf(nq2) * Kmaxb[bh] + 0.11f;
  float cr2[4], amr2[4];
#pragma unroll
  for (int r = 0; r < 4; ++r) {
    cr2[r] = __shfl(c_li, g * 4 + r) * L2E;
    amr2[r] = 0.1f * L2E * am_s[r0 + g * 4 + r];
  }

  float lpart[4] = {0.f, 0.f, 0.f, 0.f};
  f32x4 o[4];
#pragma unroll
  for (int nd = 0; nd < 4; ++nd) o[nd] = {0.f, 0.f, 0.f, 0.f};

  for (int jj = 0; jj < 8; ++jj) {
    const int j0 = (jh * 8 + jj) << 6;
    // QK^T
    f16x8 kf[4][2];
#pragma unroll
    for (int nc = 0; nc < 4; ++nc)
#pragma unroll
      for (int ks = 0; ks < 2; ++ks)
        kf[nc][ks] = *(const f16x8*)(Kh + base + (size_t)(j0 + nc * 16 + li) * 64 +
                                     ks * 32 + g * 8);
    f32x4 s[4];
#pragma unroll
    for (int nc = 0; nc < 4; ++nc) {
      f32x4 a = {0.f, 0.f, 0.f, 0.f};
      a = __builtin_amdgcn_mfma_f32_16x16x32_f16(qf[0], kf[nc][0], a, 0, 0, 0);
      a = __builtin_amdgcn_mfma_f32_16x16x32_f16(qf[1], kf[nc][1], a, 0, 0, 0);
      s[nc] = a;
    }
    // unnormalized P = 2^(s*0.125*L2E + prior*L2E - c*L2E); accumulate l
#pragma unroll
    for (int nc = 0; nc < 4; ++nc) {
      float amc = am_s[j0 + nc * 16 + li];
      int colb = (nc * 16 + li) * 2;
#pragma unroll
      for (int r = 0; r < 4; ++r) {
        float p = exp2f(s[nc][r] * (0.125f * L2E) + amr2[r] * amc - cr2[r]);
        lpart[r] += p;
        int row = g * 4 + r;
        *(h16*)(&Pst[wave][(row << 7) + (colb ^ ((row & 7) << 4))]) = (h16)p;
      }
    }
    // read A-frags back (row-major), reuse for Pg store
    f16x8 af[2];
#pragma unroll
    for (int ks = 0; ks < 2; ++ks) {
      int cb = (ks * 32 + g * 8) * 2;
      af[ks] = *(const f16x8*)(&Pst[wave][(li << 7) + (cb ^ ((li & 7) << 4))]);
      *(f16x8*)(Pg + ((size_t)bh << 20) + (size_t)(r0 + li) * 1024 + j0 +
                ks * 32 + g * 8) = af[ks];
    }
    // PV
#pragma unroll
    for (int nd = 0; nd < 4; ++nd) {
      f16x8 v0 = *(const f16x8*)(Vt + base + (size_t)(nd * 16 + li) * 1024 + j0 +
                                 g * 8);
      f16x8 v1 = *(const f16x8*)(Vt + base + (size_t)(nd * 16 + li) * 1024 + j0 +
                                 32 + g * 8);
      o[nd] = __builtin_amdgcn_mfma_f32_16x16x32_f16(af[0], v0, o[nd], 0, 0, 0);
      o[nd] = __builtin_amdgcn_mfma_f32_16x16x32_f16(af[1], v1, o[nd], 0, 0, 0);
    }
  }

  // l: reduce over the 16 lanes of each group
#pragma unroll
  for (int r = 0; r < 4; ++r) {
    lpart[r] += __shfl_xor(lpart[r], 1);
    lpart[r] += __shfl_xor(lpart[r], 2);
    lpart[r] += __shfl_xor(lpart[r], 4);
    lpart[r] += __shfl_xor(lpart[r], 8);
  }
  if (li == 0) {
#pragma unroll
    for (int r = 0; r < 4; ++r) Lsh[h][jh][g * 4 + r] = lpart[r];
  }
  __syncthreads();
  float rinv[4];
#pragma unroll
  for (int r = 0; r < 4; ++r)
    rinv[r] = 1.0f / (Lsh[h][0][g * 4 + r] + Lsh[h][1][g * 4 + r]);
  // O combine across j-halves
  if (jh == 1) {
#pragma unroll
    for (int nd = 0; nd < 4; ++nd)
#pragma unroll
      for (int r = 0; r < 4; ++r) Osh[h][g * 4 + r][nd * 16 + li] = o[nd][r];
  }
  __syncthreads();
  if (jh == 0) {
#pragma unroll
    for (int nd = 0; nd < 4; ++nd)
#pragma unroll
      for (int r = 0; r < 4; ++r) {
        float v = (o[nd][r] + Osh[h][g * 4 + r][nd * 16 + li]) * rinv[r];
        OHh[(size_t)((b << 10) + r0 + g * 4 + r) * 256 + h * 64 + nd * 16 + li] =
            (h16)v;
      }
    if (li == 0) {
#pragma unroll
      for (int r = 0; r < 4; ++r)
        rinvb[((size_t)bh << 10) + r0 + g * 4 + r] = rinv[r];
    }
  }
}

// ---------------------------------------------------------------------------
// 6) AW[b,i,j] = 0.25 * sum_h Pu[bh,i,j] * rinv[bh,i]
__global__ void k_awnorm(const h16* __restrict__ Pg,
                         const float* __restrict__ rinvb,
                         float* __restrict__ AW) {
  int idx = blockIdx.x * 256 + threadIdx.x;  // 1,048,576
  int b = idx >> 17;
  int rem = idx & 131071;
  int i = rem >> 7;
  int jc = (rem & 127) << 3;
  size_t rowbase = ((size_t)i << 10) + jc;
  float sum[8] = {0.f, 0.f, 0.f, 0.f, 0.f, 0.f, 0.f, 0.f};
#pragma unroll
  for (int h = 0; h < 4; ++h) {
    int bh = b * 4 + h;
    f16x8 pu = *(const f16x8*)(Pg + (((size_t)bh) << 20) + rowbase);
    float rv = 0.25f * rinvb[((size_t)bh << 10) + i];
#pragma unroll
    for (int e = 0; e < 8; ++e) sum[e] += (float)pu[e] * rv;
  }
  float* dst = AW + (((size_t)b) << 20) + rowbase;
  float4 o1 = {sum[0], sum[1], sum[2], sum[3]};
  float4 o2 = {sum[4], sum[5], sum[6], sum[7]};
  *(float4*)dst = o1;
  *(float4*)(dst + 4) = o2;
}

// ---------------------------------------------------------------------------
// 7) proj GEMM via MFMA: out = OHh @ proj_w^T + proj_b  (fp32 out)
__global__ __launch_bounds__(128) void k_proj(const h16* __restrict__ OHh,
                                              const h16* __restrict__ pwh,
                                              const float* __restrict__ bias,
                                              float* __restrict__ out) {
  const int w = threadIdx.x >> 6, lane = threadIdx.x & 63;
  const int g = lane >> 4, li = lane & 15;
  const int tile = blockIdx.x * 2 + w;  // 0..1023
  const int tc = tile & 3, tr = tile >> 2;
  const int r0 = tr * 32, c0 = tc * 64;
  f32x4 acc[2][4];
#pragma unroll
  for (int mr = 0; mr < 2; ++mr)
#pragma unroll
    for (int nc = 0; nc < 4; ++nc) acc[mr][nc] = {0.f, 0.f, 0.f, 0.f};
  for (int ks = 0; ks < 8; ++ks) {
    int k0 = ks * 32 + g * 8;
    f16x8 a[2], bf[4];
#pragma unroll
    for (int mr = 0; mr < 2; ++mr)
      a[mr] = *(const f16x8*)(OHh + (size_t)(r0 + mr * 16 + li) * 256 + k0);
#pragma unroll
    for (int nc = 0; nc < 4; ++nc)
      bf[nc] = *(const f16x8*)(pwh + (size_t)(c0 + nc * 16 + li) * 256 + k0);
#pragma unroll
    for (int mr = 0; mr < 2; ++mr)
#pragma unroll
      for (int nc = 0; nc < 4; ++nc)
        acc[mr][nc] = __builtin_amdgcn_mfma_f32_16x16x32_f16(a[mr], bf[nc],
                                                             acc[mr][nc], 0, 0, 0);
  }
#pragma unroll
  for (int nc = 0; nc < 4; ++nc) {
    int c = c0 + nc * 16 + li;
    float bv = bias[c];
#pragma unroll
    for (int mr = 0; mr < 2; ++mr)
#pragma unroll
      for (int r = 0; r < 4; ++r) {
        int m = r0 + mr * 16 + g * 4 + r;
        out[(size_t)m * 256 + c] = acc[mr][nc][r] + bv;
      }
  }
}

// ---------------------------------------------------------------------------
// 8) reg loss
__global__ void k_reg(const float* __restrict__ kern, float* __restrict__ out) {
  const float Cst[36] = {
      -1.f, -1.f, -1.f, 2.f, 2.f, 2.f, -1.f, -1.f, -1.f,
      -0.11111111f, 0.f, -0.11111111f, 0.f, 4.f, 0.f,
      -0.11111111f, 0.f, -0.11111111f,
      0.f, -1.f, 0.f, -1.f, 4.f, -1.f, 0.f, -1.f, 0.f,
      -1.f, 0.f, -1.f, 0.f, 4.f, 0.f, -1.f, 0.f, -1.f};
  int t = threadIdx.x;
  float v = 0.f;
  if (t < 36) {
    float kv = kern[t];
    float d = kv - Cst[t];
    v = d * d * (1.0f / 9.0f) + 0.01f * fabsf(kv);
  }
#pragma unroll
  for (int off = 32; off; off >>= 1) v += __shfl_xor(v, off);
  if (t == 0) out[0] = v;
}

// ---------------------------------------------------------------------------
extern "C" void kernel_launch(void* const* d_in, const int* in_sizes, int n_in,
                              void* d_out, int out_size, void* d_ws,
                              size_t ws_size, hipStream_t stream) {
  const float* x = (const float*)d_in[0];
  const float* qkv_w = (const float*)d_in[1];
  const float* qkv_b = (const float*)d_in[2];
  const float* proj_w = (const float*)d_in[3];
  const float* proj_b = (const float*)d_in[4];
  const float* kern = (const float*)d_in[5];

  float* out = (float*)d_out;   // [8,1024,256]
  float* aw = out + 2097152;    // [8,1024,1024]
  float* rl = out + 10485760;   // scalar

  float* xm = (float*)d_ws;        // 8192 f32
  float* amap = xm + 8192;         // 8192 f32
  float* rinvb = amap + 8192;      // 32768 f32
  float* Kmaxb = rinvb + 32768;    // 32 f32 (+pad)
  h16* xh = (h16*)(Kmaxb + 64);    // 2097152
  h16* qwh = xh + 2097152;         // 196608
  h16* pwh = qwh + 196608;         // 65536
  h16* Qh = pwh + 65536;           // 2097152  [b,h,n,64]
  h16* Kh = Qh + 2097152;          // 2097152  [b,h,n,64]
  h16* Vt = Kh + 2097152;          // 2097152  [b,h,64,1024]
  h16* OHh = Vt + 2097152;         // 2097152  [b,n,256]
  h16* Pg = OHh + 2097152;         // 33554432 [b,h,n,1024] unnormalized P

  k_cast<<<2304, 256, 0, stream>>>(x, qkv_w, proj_w, xh, qwh, pwh, xm);
  k_amap<<<32, 256, 0, stream>>>(xm, kern, amap);
  k_qkv<<<1536, 128, 0, stream>>>(xh, qwh, qkv_b, Qh, Kh, Vt);
  k_knorm<<<32, 256, 0, stream>>>(Kh, Kmaxb);
  k_attn<<<512, 512, 0, stream>>>(Qh, Kh, Vt, amap, Kmaxb, Pg, rinvb, OHh);
  k_awnorm<<<4096, 256, 0, stream>>>(Pg, rinvb, aw);
  k_proj<<<512, 128, 0, stream>>>(OHh, pwh, proj_b, out);
  k_reg<<<1, 64, 0, stream>>>(kern, rl);
}

// Round 6
// 219.781 us; speedup vs baseline: 1.0111x; 1.0111x over previous
//
#include <hip/hip_runtime.h>
#include <cstdint>

// Problem constants: B=8, N=1024, C=256, heads=4, hd=64
typedef _Float16 h16;
typedef __attribute__((ext_vector_type(8))) _Float16 f16x8;
typedef __attribute__((ext_vector_type(4))) _Float16 f16x4;
typedef __attribute__((ext_vector_type(4))) float f32x4;

#define L2E 1.44269504f           // log2(e)
#define QSCALE (0.125f * L2E)     // hd^-0.5 * log2(e)

// ---------------------------------------------------------------------------
// 1) cast x,qkv_w,proj_w -> fp16; fused xm row-mean
__global__ void k_cast(const float* __restrict__ x, const float* __restrict__ qw,
                       const float* __restrict__ pw, h16* __restrict__ xh,
                       h16* __restrict__ qwh, h16* __restrict__ pwh,
                       float* __restrict__ xm) {
  int bid = blockIdx.x, tid = threadIdx.x;
  if (bid < 2048) {  // x part
    int i4 = bid * 256 + tid;
    float4 v = ((const float4*)x)[i4];
    f16x4 o = {(h16)v.x, (h16)v.y, (h16)v.z, (h16)v.w};
    ((f16x4*)xh)[i4] = o;
    float s = v.x + v.y + v.z + v.w;
#pragma unroll
    for (int off = 32; off; off >>= 1) s += __shfl_xor(s, off);
    if ((tid & 63) == 0) xm[i4 >> 6] = s * (1.0f / 256.0f);
  } else {
    int i4 = (bid - 2048) * 256 + tid;
    if (i4 < 49152) {
      float4 v = ((const float4*)qw)[i4];
      f16x4 o = {(h16)v.x, (h16)v.y, (h16)v.z, (h16)v.w};
      ((f16x4*)qwh)[i4] = o;
    } else {
      int j = i4 - 49152;
      float4 v = ((const float4*)pw)[j];
      f16x4 o = {(h16)v.x, (h16)v.y, (h16)v.z, (h16)v.w};
      ((f16x4*)pwh)[j] = o;
    }
  }
}

// ---------------------------------------------------------------------------
// 2) amap[b,n] = sigmoid(conv3x3(xm_grid, mean_k(kernels)))  (zero pad)
__global__ void k_amap(const float* __restrict__ xm,
                       const float* __restrict__ kern,
                       float* __restrict__ amap) {
  int idx = blockIdx.x * 256 + threadIdx.x;  // 8192
  int b = idx >> 10, n = idx & 1023;
  int y = n >> 5, xq = n & 31;
  float km[9];
#pragma unroll
  for (int i = 0; i < 9; ++i)
    km[i] = 0.25f * (kern[i] + kern[9 + i] + kern[18 + i] + kern[27 + i]);
  float acc = 0.f;
#pragma unroll
  for (int dy = 0; dy < 3; ++dy) {
#pragma unroll
    for (int dx = 0; dx < 3; ++dx) {
      int yy = y + dy - 1, xx = xq + dx - 1;
      if (yy >= 0 && yy < 32 && xx >= 0 && xx < 32)
        acc += km[dy * 3 + dx] * xm[(b << 10) + (yy << 5) + xx];
    }
  }
  amap[idx] = 1.0f / (1.0f + __expf(-acc));
}

// ---------------------------------------------------------------------------
// 3) QKV GEMM via MFMA: Q/K -> [b,h,n,64], V transposed -> [b,h,64,n]
__global__ __launch_bounds__(128) void k_qkv(
    const h16* __restrict__ xh, const h16* __restrict__ qwh,
    const float* __restrict__ bias, h16* __restrict__ Qh,
    h16* __restrict__ Kh, h16* __restrict__ Vt) {
  const int w = threadIdx.x >> 6, lane = threadIdx.x & 63;
  const int g = lane >> 4, li = lane & 15;
  const int tile = blockIdx.x * 2 + w;  // 0..3071
  const int tr = tile & 255, tc = tile >> 8;
  const int r0 = tr * 32, c0 = tc * 64;
  f32x4 acc[2][4];
#pragma unroll
  for (int mr = 0; mr < 2; ++mr)
#pragma unroll
    for (int nc = 0; nc < 4; ++nc) acc[mr][nc] = {0.f, 0.f, 0.f, 0.f};
  for (int ks = 0; ks < 8; ++ks) {
    int k0 = ks * 32 + g * 8;
    f16x8 a[2], bf[4];
#pragma unroll
    for (int mr = 0; mr < 2; ++mr)
      a[mr] = *(const f16x8*)(xh + (size_t)(r0 + mr * 16 + li) * 256 + k0);
#pragma unroll
    for (int nc = 0; nc < 4; ++nc)
      bf[nc] = *(const f16x8*)(qwh + (size_t)(c0 + nc * 16 + li) * 256 + k0);
#pragma unroll
    for (int mr = 0; mr < 2; ++mr)
#pragma unroll
      for (int nc = 0; nc < 4; ++nc)
        acc[mr][nc] = __builtin_amdgcn_mfma_f32_16x16x32_f16(a[mr], bf[nc],
                                                             acc[mr][nc], 0, 0, 0);
  }
  const int which = c0 >> 8;
  const int hh = (c0 >> 6) & 3;
  const int bq = r0 >> 10;
  const size_t base = ((size_t)(bq * 4 + hh)) << 16;
  if (which == 2) {  // V: store transposed as f16x4 runs along n
#pragma unroll
    for (int nc = 0; nc < 4; ++nc) {
      int d = nc * 16 + li;
      float bv = bias[c0 + d];
#pragma unroll
      for (int mr = 0; mr < 2; ++mr) {
        int n0 = (r0 & 1023) + mr * 16 + g * 4;
        f16x4 pk = {(h16)(acc[mr][nc][0] + bv), (h16)(acc[mr][nc][1] + bv),
                    (h16)(acc[mr][nc][2] + bv), (h16)(acc[mr][nc][3] + bv)};
        *(f16x4*)(Vt + base + (size_t)d * 1024 + n0) = pk;
      }
    }
  } else {
    h16* dst = (which == 0) ? Qh : Kh;
#pragma unroll
    for (int nc = 0; nc < 4; ++nc) {
      int d = nc * 16 + li;
      float bv = bias[c0 + d];
#pragma unroll
      for (int mr = 0; mr < 2; ++mr) {
#pragma unroll
        for (int r = 0; r < 4; ++r) {
          int n = (r0 & 1023) + mr * 16 + g * 4 + r;
          dst[base + (size_t)n * 64 + d] = (h16)(acc[mr][nc][r] + bv);
        }
      }
    }
  }
}

// ---------------------------------------------------------------------------
// 4) Kmax[bh] = max_n ||K[bh,n,:]||
__global__ void k_knorm(const h16* __restrict__ Kh, float* __restrict__ Kmaxb) {
  __shared__ float red[4];
  const int tid = threadIdx.x;
  const h16* base = Kh + ((size_t)blockIdx.x << 16);
  float mx = 0.f;
#pragma unroll
  for (int i = 0; i < 4; ++i) {
    int n = i * 256 + tid;
    float s2 = 0.f;
#pragma unroll
    for (int ks = 0; ks < 8; ++ks) {
      f16x8 v = *(const f16x8*)(base + (size_t)n * 64 + ks * 8);
#pragma unroll
      for (int e = 0; e < 8; ++e) {
        float f = (float)v[e];
        s2 += f * f;
      }
    }
    mx = fmaxf(mx, s2);
  }
#pragma unroll
  for (int off = 32; off; off >>= 1) mx = fmaxf(mx, __shfl_xor(mx, off));
  if ((tid & 63) == 0) red[tid >> 6] = mx;
  __syncthreads();
  if (tid == 0) {
    mx = fmaxf(fmaxf(red[0], red[1]), fmaxf(red[2], red[3]));
    Kmaxb[blockIdx.x] = sqrtf(mx);
  }
}

// ---------------------------------------------------------------------------
// 5) k_lsum: per-row exponent offset E[bh,i] = c*log2e + log2(sum_j 2^(...-c*log2e))
//    Swapped mfma(K,Q): lane owns one q-row -> scalar stats, no LDS round-trip.
//    block = (bh, 32-row tile): 4 waves = (qsub, jh).
__global__ __launch_bounds__(256, 4) void k_lsum(
    const h16* __restrict__ Qh, const h16* __restrict__ Kh,
    const float* __restrict__ amap, const float* __restrict__ Kmaxb,
    float* __restrict__ Erow) {
  __shared__ float am_s[1024];
  __shared__ float Lsh[2][2][16];
  const int tid = threadIdx.x;
  const int wave = tid >> 6, lane = tid & 63, g = lane >> 4, li = lane & 15;
  const int qsub = wave >> 1, jh = wave & 1;
  const int bh = blockIdx.x >> 5, rt = blockIdx.x & 31;
  const int b = bh >> 2;
  const int r0 = rt * 32 + qsub * 16;
  const size_t base = ((size_t)bh) << 16;

  am_s[tid] = amap[(b << 10) + tid];
  am_s[tid + 256] = amap[(b << 10) + 256 + tid];
  am_s[tid + 512] = amap[(b << 10) + 512 + tid];
  am_s[tid + 768] = amap[(b << 10) + 768 + tid];
  __syncthreads();

  // Q fragment (B-operand): lane(g,li) holds q-row li, d = ks*32+g*8..+7
  f16x8 qf[2];
#pragma unroll
  for (int ks = 0; ks < 2; ++ks)
    qf[ks] = *(const f16x8*)(Qh + base + (size_t)(r0 + li) * 64 + ks * 32 + g * 8);

  // per-lane (row li) shift bound
  float nq2 = 0.f;
#pragma unroll
  for (int ks = 0; ks < 2; ++ks)
#pragma unroll
    for (int e = 0; e < 8; ++e) {
      float f = (float)qf[ks][e];
      nq2 += f * f;
    }
  nq2 += __shfl_xor(nq2, 16);
  nq2 += __shfl_xor(nq2, 32);
  const float c = 0.125f * sqrtf(nq2) * Kmaxb[bh] + 0.11f;
  const float mcl = -c * L2E;
  const float amr2 = 0.1f * L2E * am_s[r0 + li];
  const int prow = ((li >> 2) << 3) + (li & 3);  // permuted K-row base

  float lpart = 0.f;
  for (int jj = 0; jj < 8; ++jj) {
    const int j0 = jh * 512 + jj * 64;
#pragma unroll
    for (int u = 0; u < 2; ++u) {
#pragma unroll
      for (int ab = 0; ab < 2; ++ab) {
        const int rK = j0 + u * 32 + ab * 4 + prow;
        f16x8 k0 = *(const f16x8*)(Kh + base + (size_t)rK * 64 + g * 8);
        f16x8 k1 = *(const f16x8*)(Kh + base + (size_t)rK * 64 + 32 + g * 8);
        f32x4 s = {0.f, 0.f, 0.f, 0.f};
        s = __builtin_amdgcn_mfma_f32_16x16x32_f16(k0, qf[0], s, 0, 0, 0);
        s = __builtin_amdgcn_mfma_f32_16x16x32_f16(k1, qf[1], s, 0, 0, 0);
        f32x4 am4 = *(const f32x4*)&am_s[j0 + u * 32 + g * 8 + ab * 4];
#pragma unroll
        for (int r = 0; r < 4; ++r) {
          float pre = fmaf(amr2, am4[r], mcl);
          lpart += exp2f(fmaf(s[r], QSCALE, pre));
        }
      }
    }
  }
  lpart += __shfl_xor(lpart, 16);
  lpart += __shfl_xor(lpart, 32);
  if (g == 0) Lsh[qsub][jh][li] = lpart;
  __syncthreads();
  if (jh == 0 && g == 0) {
    float l = Lsh[qsub][0][li] + Lsh[qsub][1][li];
    Erow[((size_t)bh << 10) + r0 + li] = c * L2E + __log2f(l);
  }
}

// ---------------------------------------------------------------------------
// 6) fused attention v2: normalized P in-register (permuted-row S^T mfma),
//    PV via O^T mfma, AW head-mean reduced in LDS per jj-tile. No P in HBM.
//    block = (b, 16-row tile), 8 waves = (head, j-half).
__global__ __launch_bounds__(512, 4) void k_attn(
    const h16* __restrict__ Qh, const h16* __restrict__ Kh,
    const h16* __restrict__ Vt, const float* __restrict__ amap,
    const float* __restrict__ Erow, float* __restrict__ AW,
    h16* __restrict__ OHh) {
  __shared__ float am_s[1024];
  __shared__ __align__(16) unsigned char Pst[8][2048];  // per-wave 16x64 h16, swizzled
  __shared__ float Osh[4][16][68];

  const int tid = threadIdx.x;
  const int wave = tid >> 6, lane = tid & 63, g = lane >> 4, li = lane & 15;
  const int h = wave >> 1, jh = wave & 1;
  const int b = blockIdx.x & 7, rt = blockIdx.x >> 3;
  const int r0 = rt * 16;
  const int bh = b * 4 + h;
  const size_t base = ((size_t)bh) << 16;

  am_s[tid] = amap[(b << 10) + tid];
  am_s[tid + 512] = amap[(b << 10) + 512 + tid];
  __syncthreads();

  f16x8 qf[2];
#pragma unroll
  for (int ks = 0; ks < 2; ++ks)
    qf[ks] = *(const f16x8*)(Qh + base + (size_t)(r0 + li) * 64 + ks * 32 + g * 8);

  const float E = Erow[((size_t)bh << 10) + r0 + li];  // per-lane row offset
  const float amr2 = 0.1f * L2E * am_s[r0 + li];
  const int prow = ((li >> 2) << 3) + (li & 3);
  const int swz = (li & 7) << 4;

  f32x4 o[4];
#pragma unroll
  for (int nd = 0; nd < 4; ++nd) o[nd] = {0.f, 0.f, 0.f, 0.f};

  const int arow = tid >> 5, ac = (tid & 31) << 2;   // AW-reduce assignment
  const int ahalf = ac >> 6, aci = ac & 63;
  const int aswz = (arow & 7) << 4;

  for (int jj = 0; jj < 8; ++jj) {
    const int j0 = jh * 512 + jj * 64;
    // ---- QK^T (S^T form, permuted K rows) + normalized P ----
    f16x8 bfrag[2];
#pragma unroll
    for (int u = 0; u < 2; ++u) {
      f32x4 s[2];
      f32x4 am4[2];
#pragma unroll
      for (int ab = 0; ab < 2; ++ab) {
        const int rK = j0 + u * 32 + ab * 4 + prow;
        f16x8 k0 = *(const f16x8*)(Kh + base + (size_t)rK * 64 + g * 8);
        f16x8 k1 = *(const f16x8*)(Kh + base + (size_t)rK * 64 + 32 + g * 8);
        f32x4 a = {0.f, 0.f, 0.f, 0.f};
        a = __builtin_amdgcn_mfma_f32_16x16x32_f16(k0, qf[0], a, 0, 0, 0);
        a = __builtin_amdgcn_mfma_f32_16x16x32_f16(k1, qf[1], a, 0, 0, 0);
        s[ab] = a;
        am4[ab] = *(const f32x4*)&am_s[j0 + u * 32 + g * 8 + ab * 4];
      }
      f16x8 bf;
#pragma unroll
      for (int ab = 0; ab < 2; ++ab)
#pragma unroll
        for (int r = 0; r < 4; ++r) {
          float pre = fmaf(amr2, am4[ab][r], -E);
          bf[ab * 4 + r] = (h16)exp2f(fmaf(s[ab][r], QSCALE, pre));
        }
      bfrag[u] = bf;
      *(f16x8*)(&Pst[wave][(li << 7) + ((u * 64 + g * 16) ^ swz)]) = bf;
    }
    // ---- PV (O^T = V^T * P^T), register-only ----
#pragma unroll
    for (int nd = 0; nd < 4; ++nd) {
      f16x8 v0 = *(const f16x8*)(Vt + base + (size_t)(nd * 16 + li) * 1024 + j0 + g * 8);
      f16x8 v1 = *(const f16x8*)(Vt + base + (size_t)(nd * 16 + li) * 1024 + j0 + 32 + g * 8);
      o[nd] = __builtin_amdgcn_mfma_f32_16x16x32_f16(v0, bfrag[0], o[nd], 0, 0, 0);
      o[nd] = __builtin_amdgcn_mfma_f32_16x16x32_f16(v1, bfrag[1], o[nd], 0, 0, 0);
    }
    __syncthreads();
    // ---- AW head-mean: each thread 4 cols of one row ----
    {
      float s0 = 0.f, s1 = 0.f, s2 = 0.f, s3 = 0.f;
#pragma unroll
      for (int h2 = 0; h2 < 4; ++h2) {
        f16x4 v = *(const f16x4*)(&Pst[h2 * 2 + ahalf][(arow << 7) + ((aci * 2) ^ aswz)]);
        s0 += (float)v[0]; s1 += (float)v[1]; s2 += (float)v[2]; s3 += (float)v[3];
      }
      const int colg = ahalf * 512 + jj * 64 + aci;
      float4 ov = {0.25f * s0, 0.25f * s1, 0.25f * s2, 0.25f * s3};
      *(float4*)(AW + ((size_t)b << 20) + (size_t)(r0 + arow) * 1024 + colg) = ov;
    }
    __syncthreads();
  }
  // ---- epilogue: combine O across j-halves, write OHh ----
  if (jh == 1) {
#pragma unroll
    for (int nd = 0; nd < 4; ++nd)
      *(f32x4*)&Osh[h][li][nd * 16 + g * 4] = o[nd];
  }
  __syncthreads();
  if (jh == 0) {
#pragma unroll
    for (int nd = 0; nd < 4; ++nd) {
      f32x4 p = *(const f32x4*)&Osh[h][li][nd * 16 + g * 4];
      f16x4 pk = {(h16)(o[nd][0] + p[0]), (h16)(o[nd][1] + p[1]),
                  (h16)(o[nd][2] + p[2]), (h16)(o[nd][3] + p[3])};
      *(f16x4*)(OHh + (size_t)((b << 10) + r0 + li) * 256 + h * 64 + nd * 16 + g * 4) = pk;
    }
  }
}

// ---------------------------------------------------------------------------
// 7) proj GEMM via MFMA: out = OHh @ proj_w^T + proj_b  (fp32 out)
__global__ __launch_bounds__(128) void k_proj(const h16* __restrict__ OHh,
                                              const h16* __restrict__ pwh,
                                              const float* __restrict__ bias,
                                              float* __restrict__ out) {
  const int w = threadIdx.x >> 6, lane = threadIdx.x & 63;
  const int g = lane >> 4, li = lane & 15;
  const int tile = blockIdx.x * 2 + w;  // 0..1023
  const int tc = tile & 3, tr = tile >> 2;
  const int r0 = tr * 32, c0 = tc * 64;
  f32x4 acc[2][4];
#pragma unroll
  for (int mr = 0; mr < 2; ++mr)
#pragma unroll
    for (int nc = 0; nc < 4; ++nc) acc[mr][nc] = {0.f, 0.f, 0.f, 0.f};
  for (int ks = 0; ks < 8; ++ks) {
    int k0 = ks * 32 + g * 8;
    f16x8 a[2], bf[4];
#pragma unroll
    for (int mr = 0; mr < 2; ++mr)
      a[mr] = *(const f16x8*)(OHh + (size_t)(r0 + mr * 16 + li) * 256 + k0);
#pragma unroll
    for (int nc = 0; nc < 4; ++nc)
      bf[nc] = *(const f16x8*)(pwh + (size_t)(c0 + nc * 16 + li) * 256 + k0);
#pragma unroll
    for (int mr = 0; mr < 2; ++mr)
#pragma unroll
      for (int nc = 0; nc < 4; ++nc)
        acc[mr][nc] = __builtin_amdgcn_mfma_f32_16x16x32_f16(a[mr], bf[nc],
                                                             acc[mr][nc], 0, 0, 0);
  }
#pragma unroll
  for (int nc = 0; nc < 4; ++nc) {
    int cc = c0 + nc * 16 + li;
    float bv = bias[cc];
#pragma unroll
    for (int mr = 0; mr < 2; ++mr)
#pragma unroll
      for (int r = 0; r < 4; ++r) {
        int m = r0 + mr * 16 + g * 4 + r;
        out[(size_t)m * 256 + cc] = acc[mr][nc][r] + bv;
      }
  }
}

// ---------------------------------------------------------------------------
// 8) reg loss
__global__ void k_reg(const float* __restrict__ kern, float* __restrict__ out) {
  const float Cst[36] = {
      -1.f, -1.f, -1.f, 2.f, 2.f, 2.f, -1.f, -1.f, -1.f,
      -0.11111111f, 0.f, -0.11111111f, 0.f, 4.f, 0.f,
      -0.11111111f, 0.f, -0.11111111f,
      0.f, -1.f, 0.f, -1.f, 4.f, -1.f, 0.f, -1.f, 0.f,
      -1.f, 0.f, -1.f, 0.f, 4.f, 0.f, -1.f, 0.f, -1.f};
  int t = threadIdx.x;
  float v = 0.f;
  if (t < 36) {
    float kv = kern[t];
    float d = kv - Cst[t];
    v = d * d * (1.0f / 9.0f) + 0.01f * fabsf(kv);
  }
#pragma unroll
  for (int off = 32; off; off >>= 1) v += __shfl_xor(v, off);
  if (t == 0) out[0] = v;
}

// ---------------------------------------------------------------------------
extern "C" void kernel_launch(void* const* d_in, const int* in_sizes, int n_in,
                              void* d_out, int out_size, void* d_ws,
                              size_t ws_size, hipStream_t stream) {
  const float* x = (const float*)d_in[0];
  const float* qkv_w = (const float*)d_in[1];
  const float* qkv_b = (const float*)d_in[2];
  const float* proj_w = (const float*)d_in[3];
  const float* proj_b = (const float*)d_in[4];
  const float* kern = (const float*)d_in[5];

  float* out = (float*)d_out;   // [8,1024,256]
  float* aw = out + 2097152;    // [8,1024,1024]
  float* rl = out + 10485760;   // scalar

  float* xm = (float*)d_ws;        // 8192 f32
  float* amap = xm + 8192;         // 8192 f32
  float* Erow = amap + 8192;       // 32768 f32 [bh,n]
  float* Kmaxb = Erow + 32768;     // 32 f32 (+pad)
  h16* xh = (h16*)(Kmaxb + 64);    // 2097152
  h16* qwh = xh + 2097152;         // 196608
  h16* pwh = qwh + 196608;         // 65536
  h16* Qh = pwh + 65536;           // 2097152  [b,h,n,64]
  h16* Kh = Qh + 2097152;          // 2097152  [b,h,n,64]
  h16* Vt = Kh + 2097152;          // 2097152  [b,h,64,1024]
  h16* OHh = Vt + 2097152;         // 2097152  [b,n,256]

  k_cast<<<2304, 256, 0, stream>>>(x, qkv_w, proj_w, xh, qwh, pwh, xm);
  k_amap<<<32, 256, 0, stream>>>(xm, kern, amap);
  k_qkv<<<1536, 128, 0, stream>>>(xh, qwh, qkv_b, Qh, Kh, Vt);
  k_knorm<<<32, 256, 0, stream>>>(Kh, Kmaxb);
  k_lsum<<<1024, 256, 0, stream>>>(Qh, Kh, amap, Kmaxb, Erow);
  k_attn<<<512, 512, 0, stream>>>(Qh, Kh, Vt, amap, Erow, aw, OHh);
  k_proj<<<512, 128, 0, stream>>>(OHh, pwh, proj_b, out);
  k_reg<<<1, 64, 0, stream>>>(kern, rl);
}

// Round 7
// 215.046 us; speedup vs baseline: 1.0333x; 1.0220x over previous
//
#include <hip/hip_runtime.h>
#include <cstdint>

// Problem constants: B=8, N=1024, C=256, heads=4, hd=64
typedef _Float16 h16;
typedef __attribute__((ext_vector_type(8))) _Float16 f16x8;
typedef __attribute__((ext_vector_type(4))) _Float16 f16x4;
typedef __attribute__((ext_vector_type(4))) float f32x4;

#define L2E 1.44269504f           // log2(e)
#define QSCALE (0.125f * L2E)     // hd^-0.5 * log2(e)

// ---------------------------------------------------------------------------
// 1) cast x,qkv_w,proj_w -> fp16; fused xm row-mean
__global__ void k_cast(const float* __restrict__ x, const float* __restrict__ qw,
                       const float* __restrict__ pw, h16* __restrict__ xh,
                       h16* __restrict__ qwh, h16* __restrict__ pwh,
                       float* __restrict__ xm) {
  int bid = blockIdx.x, tid = threadIdx.x;
  if (bid < 2048) {  // x part
    int i4 = bid * 256 + tid;
    float4 v = ((const float4*)x)[i4];
    f16x4 o = {(h16)v.x, (h16)v.y, (h16)v.z, (h16)v.w};
    ((f16x4*)xh)[i4] = o;
    float s = v.x + v.y + v.z + v.w;
#pragma unroll
    for (int off = 32; off; off >>= 1) s += __shfl_xor(s, off);
    if ((tid & 63) == 0) xm[i4 >> 6] = s * (1.0f / 256.0f);
  } else {
    int i4 = (bid - 2048) * 256 + tid;
    if (i4 < 49152) {
      float4 v = ((const float4*)qw)[i4];
      f16x4 o = {(h16)v.x, (h16)v.y, (h16)v.z, (h16)v.w};
      ((f16x4*)qwh)[i4] = o;
    } else {
      int j = i4 - 49152;
      float4 v = ((const float4*)pw)[j];
      f16x4 o = {(h16)v.x, (h16)v.y, (h16)v.z, (h16)v.w};
      ((f16x4*)pwh)[j] = o;
    }
  }
}

// ---------------------------------------------------------------------------
// 2) amap[b,n] = sigmoid(conv3x3(xm_grid, mean_k(kernels)))  (zero pad)
__global__ void k_amap(const float* __restrict__ xm,
                       const float* __restrict__ kern,
                       float* __restrict__ amap) {
  int idx = blockIdx.x * 256 + threadIdx.x;  // 8192
  int b = idx >> 10, n = idx & 1023;
  int y = n >> 5, xq = n & 31;
  float km[9];
#pragma unroll
  for (int i = 0; i < 9; ++i)
    km[i] = 0.25f * (kern[i] + kern[9 + i] + kern[18 + i] + kern[27 + i]);
  float acc = 0.f;
#pragma unroll
  for (int dy = 0; dy < 3; ++dy) {
#pragma unroll
    for (int dx = 0; dx < 3; ++dx) {
      int yy = y + dy - 1, xx = xq + dx - 1;
      if (yy >= 0 && yy < 32 && xx >= 0 && xx < 32)
        acc += km[dy * 3 + dx] * xm[(b << 10) + (yy << 5) + xx];
    }
  }
  amap[idx] = 1.0f / (1.0f + __expf(-acc));
}

// ---------------------------------------------------------------------------
// 3) QKV GEMM via MFMA: Q/K -> [b,h,n,64], V transposed -> [b,h,64,n]
__global__ __launch_bounds__(128) void k_qkv(
    const h16* __restrict__ xh, const h16* __restrict__ qwh,
    const float* __restrict__ bias, h16* __restrict__ Qh,
    h16* __restrict__ Kh, h16* __restrict__ Vt) {
  const int w = threadIdx.x >> 6, lane = threadIdx.x & 63;
  const int g = lane >> 4, li = lane & 15;
  const int tile = blockIdx.x * 2 + w;  // 0..3071
  const int tr = tile & 255, tc = tile >> 8;
  const int r0 = tr * 32, c0 = tc * 64;
  f32x4 acc[2][4];
#pragma unroll
  for (int mr = 0; mr < 2; ++mr)
#pragma unroll
    for (int nc = 0; nc < 4; ++nc) acc[mr][nc] = {0.f, 0.f, 0.f, 0.f};
  for (int ks = 0; ks < 8; ++ks) {
    int k0 = ks * 32 + g * 8;
    f16x8 a[2], bf[4];
#pragma unroll
    for (int mr = 0; mr < 2; ++mr)
      a[mr] = *(const f16x8*)(xh + (size_t)(r0 + mr * 16 + li) * 256 + k0);
#pragma unroll
    for (int nc = 0; nc < 4; ++nc)
      bf[nc] = *(const f16x8*)(qwh + (size_t)(c0 + nc * 16 + li) * 256 + k0);
#pragma unroll
    for (int mr = 0; mr < 2; ++mr)
#pragma unroll
      for (int nc = 0; nc < 4; ++nc)
        acc[mr][nc] = __builtin_amdgcn_mfma_f32_16x16x32_f16(a[mr], bf[nc],
                                                             acc[mr][nc], 0, 0, 0);
  }
  const int which = c0 >> 8;
  const int hh = (c0 >> 6) & 3;
  const int bq = r0 >> 10;
  const size_t base = ((size_t)(bq * 4 + hh)) << 16;
  if (which == 2) {  // V: store transposed as f16x4 runs along n
#pragma unroll
    for (int nc = 0; nc < 4; ++nc) {
      int d = nc * 16 + li;
      float bv = bias[c0 + d];
#pragma unroll
      for (int mr = 0; mr < 2; ++mr) {
        int n0 = (r0 & 1023) + mr * 16 + g * 4;
        f16x4 pk = {(h16)(acc[mr][nc][0] + bv), (h16)(acc[mr][nc][1] + bv),
                    (h16)(acc[mr][nc][2] + bv), (h16)(acc[mr][nc][3] + bv)};
        *(f16x4*)(Vt + base + (size_t)d * 1024 + n0) = pk;
      }
    }
  } else {
    h16* dst = (which == 0) ? Qh : Kh;
#pragma unroll
    for (int nc = 0; nc < 4; ++nc) {
      int d = nc * 16 + li;
      float bv = bias[c0 + d];
#pragma unroll
      for (int mr = 0; mr < 2; ++mr) {
#pragma unroll
        for (int r = 0; r < 4; ++r) {
          int n = (r0 & 1023) + mr * 16 + g * 4 + r;
          dst[base + (size_t)n * 64 + d] = (h16)(acc[mr][nc][r] + bv);
        }
      }
    }
  }
}

// ---------------------------------------------------------------------------
// 4) Kmax[bh] = max_n ||K[bh,n,:]||
__global__ void k_knorm(const h16* __restrict__ Kh, float* __restrict__ Kmaxb) {
  __shared__ float red[4];
  const int tid = threadIdx.x;
  const h16* base = Kh + ((size_t)blockIdx.x << 16);
  float mx = 0.f;
#pragma unroll
  for (int i = 0; i < 4; ++i) {
    int n = i * 256 + tid;
    float s2 = 0.f;
#pragma unroll
    for (int ks = 0; ks < 8; ++ks) {
      f16x8 v = *(const f16x8*)(base + (size_t)n * 64 + ks * 8);
#pragma unroll
      for (int e = 0; e < 8; ++e) {
        float f = (float)v[e];
        s2 += f * f;
      }
    }
    mx = fmaxf(mx, s2);
  }
#pragma unroll
  for (int off = 32; off; off >>= 1) mx = fmaxf(mx, __shfl_xor(mx, off));
  if ((tid & 63) == 0) red[tid >> 6] = mx;
  __syncthreads();
  if (tid == 0) {
    mx = fmaxf(fmaxf(red[0], red[1]), fmaxf(red[2], red[3]));
    Kmaxb[blockIdx.x] = sqrtf(mx);
  }
}

// ---------------------------------------------------------------------------
// 5) fused attention (merged lsum+attn):
//    pass A: per-lane row expsum -> E (registers + one LDS exchange)
//    pass B: normalized P in-register (permuted-row S^T mfma), PV via O^T mfma,
//            AW head-mean per j-pair. P never touches HBM. No rescale needed.
//    block = (b, 16-row tile), 8 waves = (head, j-half).
__global__ __launch_bounds__(512, 4) void k_fattn(
    const h16* __restrict__ Qh, const h16* __restrict__ Kh,
    const h16* __restrict__ Vt, const float* __restrict__ amap,
    const float* __restrict__ Kmaxb, float* __restrict__ AW,
    h16* __restrict__ OHh) {
  __shared__ float am_s[1024];
  __shared__ float Lsh[4][2][16];
  __shared__ __align__(16) unsigned char Pst[8][2][2048];  // [wave][jjbit][16x64 swz h16]

  const int tid = threadIdx.x;
  const int wave = tid >> 6, lane = tid & 63, g = lane >> 4, li = lane & 15;
  const int h = wave >> 1, jh = wave & 1;
  const int b = blockIdx.x & 7, rt = blockIdx.x >> 3;
  const int r0 = rt * 16;
  const int bh = b * 4 + h;
  const size_t base = ((size_t)bh) << 16;

  am_s[tid] = amap[(b << 10) + tid];
  am_s[tid + 512] = amap[(b << 10) + 512 + tid];
  __syncthreads();

  // Q fragment (B-operand): lane(g,li) holds q-row r0+li, d = ks*32+g*8..+7
  f16x8 qf[2];
#pragma unroll
  for (int ks = 0; ks < 2; ++ks)
    qf[ks] = *(const f16x8*)(Qh + base + (size_t)(r0 + li) * 64 + ks * 32 + g * 8);

  // per-lane (row li) shift bound c = 0.125*||q||*Kmax + margin
  float nq2 = 0.f;
#pragma unroll
  for (int ks = 0; ks < 2; ++ks)
#pragma unroll
    for (int e = 0; e < 8; ++e) {
      float f = (float)qf[ks][e];
      nq2 += f * f;
    }
  nq2 += __shfl_xor(nq2, 16);
  nq2 += __shfl_xor(nq2, 32);
  const float c = 0.125f * sqrtf(nq2) * Kmaxb[bh] + 0.11f;
  const float mcl = -c * L2E;
  const float amr2 = 0.1f * L2E * am_s[r0 + li];
  const int prow = ((li >> 2) << 3) + (li & 3);  // permuted K-row base
  const int swz = (li & 7) << 4;

  // ---- pass A: row expsum (shift c) ----
  float lpart = 0.f;
  for (int jj = 0; jj < 8; ++jj) {
    const int j0 = jh * 512 + jj * 64;
#pragma unroll
    for (int u = 0; u < 2; ++u) {
#pragma unroll
      for (int ab = 0; ab < 2; ++ab) {
        const int rK = j0 + u * 32 + ab * 4 + prow;
        f16x8 k0 = *(const f16x8*)(Kh + base + (size_t)rK * 64 + g * 8);
        f16x8 k1 = *(const f16x8*)(Kh + base + (size_t)rK * 64 + 32 + g * 8);
        f32x4 s = {0.f, 0.f, 0.f, 0.f};
        s = __builtin_amdgcn_mfma_f32_16x16x32_f16(k0, qf[0], s, 0, 0, 0);
        s = __builtin_amdgcn_mfma_f32_16x16x32_f16(k1, qf[1], s, 0, 0, 0);
        f32x4 am4 = *(const f32x4*)&am_s[j0 + u * 32 + g * 8 + ab * 4];
#pragma unroll
        for (int r = 0; r < 4; ++r)
          lpart += exp2f(fmaf(s[r], QSCALE, fmaf(amr2, am4[r], mcl)));
      }
    }
  }
  lpart += __shfl_xor(lpart, 16);
  lpart += __shfl_xor(lpart, 32);
  if (lane < 16) Lsh[h][jh][li] = lpart;
  __syncthreads();
  // E = c*log2e + log2(row expsum): normalizes both P and O directly
  const float E = c * L2E + __log2f(Lsh[h][0][li] + Lsh[h][1][li]);

  // ---- pass B: P (normalized) -> Pst + PV; AW per j-pair ----
  f32x4 o[4];
#pragma unroll
  for (int nd = 0; nd < 4; ++nd) o[nd] = {0.f, 0.f, 0.f, 0.f};

  const int ar = tid >> 5, ac8 = (tid & 31) << 3;  // AW-reduce: row, 8 cols
  const int ahalf = ac8 >> 7, ajj = (ac8 >> 6) & 1, acin = ac8 & 63;
  const int aswz = (ar & 7) << 4;

  for (int pj = 0; pj < 4; ++pj) {
    f16x8 bf[2][2];
#pragma unroll
    for (int q2 = 0; q2 < 2; ++q2) {
      const int j0 = jh * 512 + (pj * 2 + q2) * 64;
#pragma unroll
      for (int u = 0; u < 2; ++u) {
        f32x4 s[2];
        f32x4 am4[2];
#pragma unroll
        for (int ab = 0; ab < 2; ++ab) {
          const int rK = j0 + u * 32 + ab * 4 + prow;
          f16x8 k0 = *(const f16x8*)(Kh + base + (size_t)rK * 64 + g * 8);
          f16x8 k1 = *(const f16x8*)(Kh + base + (size_t)rK * 64 + 32 + g * 8);
          f32x4 a = {0.f, 0.f, 0.f, 0.f};
          a = __builtin_amdgcn_mfma_f32_16x16x32_f16(k0, qf[0], a, 0, 0, 0);
          a = __builtin_amdgcn_mfma_f32_16x16x32_f16(k1, qf[1], a, 0, 0, 0);
          s[ab] = a;
          am4[ab] = *(const f32x4*)&am_s[j0 + u * 32 + g * 8 + ab * 4];
        }
        f16x8 pk;
#pragma unroll
        for (int ab = 0; ab < 2; ++ab)
#pragma unroll
          for (int r = 0; r < 4; ++r)
            pk[ab * 4 + r] =
                (h16)exp2f(fmaf(s[ab][r], QSCALE, fmaf(amr2, am4[ab][r], -E)));
        bf[q2][u] = pk;
        *(f16x8*)(&Pst[wave][q2][(li << 7) + ((u * 64 + g * 16) ^ swz)]) = pk;
      }
    }
    // PV (register-only A/B): o += V^T * P^T for both jj of the pair
#pragma unroll
    for (int nd = 0; nd < 4; ++nd) {
      const h16* vb = Vt + base + (size_t)(nd * 16 + li) * 1024;
#pragma unroll
      for (int q2 = 0; q2 < 2; ++q2) {
        const int j0 = jh * 512 + (pj * 2 + q2) * 64;
        f16x8 v0 = *(const f16x8*)(vb + j0 + g * 8);
        f16x8 v1 = *(const f16x8*)(vb + j0 + 32 + g * 8);
        o[nd] = __builtin_amdgcn_mfma_f32_16x16x32_f16(v0, bf[q2][0], o[nd], 0, 0, 0);
        o[nd] = __builtin_amdgcn_mfma_f32_16x16x32_f16(v1, bf[q2][1], o[nd], 0, 0, 0);
      }
    }
    __syncthreads();
    // AW head-mean for this pair: 16 rows x 256 cols (2 halves x 2 jj x 64)
    {
      float s0 = 0.f, s1 = 0.f, s2 = 0.f, s3 = 0.f;
      float s4 = 0.f, s5 = 0.f, s6 = 0.f, s7 = 0.f;
#pragma unroll
      for (int h2 = 0; h2 < 4; ++h2) {
        f16x8 v = *(const f16x8*)(&Pst[h2 * 2 + ahalf][ajj][(ar << 7) +
                                                           ((acin * 2) ^ aswz)]);
        s0 += (float)v[0]; s1 += (float)v[1]; s2 += (float)v[2]; s3 += (float)v[3];
        s4 += (float)v[4]; s5 += (float)v[5]; s6 += (float)v[6]; s7 += (float)v[7];
      }
      const int colg = ahalf * 512 + (pj * 2 + ajj) * 64 + acin;
      float* dst = AW + ((size_t)b << 20) + (size_t)(r0 + ar) * 1024 + colg;
      float4 o1 = {0.25f * s0, 0.25f * s1, 0.25f * s2, 0.25f * s3};
      float4 o2 = {0.25f * s4, 0.25f * s5, 0.25f * s6, 0.25f * s7};
      *(float4*)dst = o1;
      *(float4*)(dst + 4) = o2;
    }
    __syncthreads();
  }

  // ---- epilogue: combine O across j-halves (reuse Pst as fp32 scratch) ----
  float* Osh = (float*)&Pst[0][0][0];  // 4 heads x 16 rows x 64 f32 = 16 KB
  if (jh == 1) {
#pragma unroll
    for (int nd = 0; nd < 4; ++nd)
      *(f32x4*)&Osh[((h * 16 + li) << 6) + nd * 16 + g * 4] = o[nd];
  }
  __syncthreads();
  if (jh == 0) {
#pragma unroll
    for (int nd = 0; nd < 4; ++nd) {
      f32x4 p = *(const f32x4*)&Osh[((h * 16 + li) << 6) + nd * 16 + g * 4];
      f16x4 pk = {(h16)(o[nd][0] + p[0]), (h16)(o[nd][1] + p[1]),
                  (h16)(o[nd][2] + p[2]), (h16)(o[nd][3] + p[3])};
      *(f16x4*)(OHh + (size_t)((b << 10) + r0 + li) * 256 + h * 64 + nd * 16 +
                g * 4) = pk;
    }
  }
}

// ---------------------------------------------------------------------------
// 6) proj GEMM via MFMA: out = OHh @ proj_w^T + proj_b  (fp32 out)
__global__ __launch_bounds__(128) void k_proj(const h16* __restrict__ OHh,
                                              const h16* __restrict__ pwh,
                                              const float* __restrict__ bias,
                                              float* __restrict__ out) {
  const int w = threadIdx.x >> 6, lane = threadIdx.x & 63;
  const int g = lane >> 4, li = lane & 15;
  const int tile = blockIdx.x * 2 + w;  // 0..1023
  const int tc = tile & 3, tr = tile >> 2;
  const int r0 = tr * 32, c0 = tc * 64;
  f32x4 acc[2][4];
#pragma unroll
  for (int mr = 0; mr < 2; ++mr)
#pragma unroll
    for (int nc = 0; nc < 4; ++nc) acc[mr][nc] = {0.f, 0.f, 0.f, 0.f};
  for (int ks = 0; ks < 8; ++ks) {
    int k0 = ks * 32 + g * 8;
    f16x8 a[2], bf[4];
#pragma unroll
    for (int mr = 0; mr < 2; ++mr)
      a[mr] = *(const f16x8*)(OHh + (size_t)(r0 + mr * 16 + li) * 256 + k0);
#pragma unroll
    for (int nc = 0; nc < 4; ++nc)
      bf[nc] = *(const f16x8*)(pwh + (size_t)(c0 + nc * 16 + li) * 256 + k0);
#pragma unroll
    for (int mr = 0; mr < 2; ++mr)
#pragma unroll
      for (int nc = 0; nc < 4; ++nc)
        acc[mr][nc] = __builtin_amdgcn_mfma_f32_16x16x32_f16(a[mr], bf[nc],
                                                             acc[mr][nc], 0, 0, 0);
  }
#pragma unroll
  for (int nc = 0; nc < 4; ++nc) {
    int cc = c0 + nc * 16 + li;
    float bv = bias[cc];
#pragma unroll
    for (int mr = 0; mr < 2; ++mr)
#pragma unroll
      for (int r = 0; r < 4; ++r) {
        int m = r0 + mr * 16 + g * 4 + r;
        out[(size_t)m * 256 + cc] = acc[mr][nc][r] + bv;
      }
  }
}

// ---------------------------------------------------------------------------
// 7) reg loss
__global__ void k_reg(const float* __restrict__ kern, float* __restrict__ out) {
  const float Cst[36] = {
      -1.f, -1.f, -1.f, 2.f, 2.f, 2.f, -1.f, -1.f, -1.f,
      -0.11111111f, 0.f, -0.11111111f, 0.f, 4.f, 0.f,
      -0.11111111f, 0.f, -0.11111111f,
      0.f, -1.f, 0.f, -1.f, 4.f, -1.f, 0.f, -1.f, 0.f,
      -1.f, 0.f, -1.f, 0.f, 4.f, 0.f, -1.f, 0.f, -1.f};
  int t = threadIdx.x;
  float v = 0.f;
  if (t < 36) {
    float kv = kern[t];
    float d = kv - Cst[t];
    v = d * d * (1.0f / 9.0f) + 0.01f * fabsf(kv);
  }
#pragma unroll
  for (int off = 32; off; off >>= 1) v += __shfl_xor(v, off);
  if (t == 0) out[0] = v;
}

// ---------------------------------------------------------------------------
extern "C" void kernel_launch(void* const* d_in, const int* in_sizes, int n_in,
                              void* d_out, int out_size, void* d_ws,
                              size_t ws_size, hipStream_t stream) {
  const float* x = (const float*)d_in[0];
  const float* qkv_w = (const float*)d_in[1];
  const float* qkv_b = (const float*)d_in[2];
  const float* proj_w = (const float*)d_in[3];
  const float* proj_b = (const float*)d_in[4];
  const float* kern = (const float*)d_in[5];

  float* out = (float*)d_out;   // [8,1024,256]
  float* aw = out + 2097152;    // [8,1024,1024]
  float* rl = out + 10485760;   // scalar

  float* xm = (float*)d_ws;        // 8192 f32
  float* amap = xm + 8192;         // 8192 f32
  float* Kmaxb = amap + 8192;      // 32 f32 (+pad)
  h16* xh = (h16*)(Kmaxb + 64);    // 2097152
  h16* qwh = xh + 2097152;         // 196608
  h16* pwh = qwh + 196608;         // 65536
  h16* Qh = pwh + 65536;           // 2097152  [b,h,n,64]
  h16* Kh = Qh + 2097152;          // 2097152  [b,h,n,64]
  h16* Vt = Kh + 2097152;          // 2097152  [b,h,64,1024]
  h16* OHh = Vt + 2097152;         // 2097152  [b,n,256]

  k_cast<<<2304, 256, 0, stream>>>(x, qkv_w, proj_w, xh, qwh, pwh, xm);
  k_amap<<<32, 256, 0, stream>>>(xm, kern, amap);
  k_qkv<<<1536, 128, 0, stream>>>(xh, qwh, qkv_b, Qh, Kh, Vt);
  k_knorm<<<32, 256, 0, stream>>>(Kh, Kmaxb);
  k_fattn<<<512, 512, 0, stream>>>(Qh, Kh, Vt, amap, Kmaxb, aw, OHh);
  k_proj<<<512, 128, 0, stream>>>(OHh, pwh, proj_b, out);
  k_reg<<<1, 64, 0, stream>>>(kern, rl);
}